// Round 1
// baseline (465.506 us; speedup 1.0000x reference)
//
#include <hip/hip_runtime.h>
#include <math.h>

#define HH 128
#define WW 128
#define HWSZ (HH*WW)
#define CH 64
#define OC 64
#define NB 8
#define CC 16
#define KC (CC*9)   // 144

// ---------------- Kernel A: per-pixel offset params ----------------
// offs layout: [b][4][H][W]: plane0=sin, plane1=cos, plane2=wr*r, plane3=wr
__global__ __launch_bounds__(256) void offsets_kernel(
    const float* __restrict__ x,
    const float* __restrict__ w_rot, const float* __restrict__ b_rot,
    const float* __restrict__ w_str, const float* __restrict__ b_str,
    const float* __restrict__ w_whl, const float* __restrict__ b_whl,
    float* __restrict__ offs)
{
    __shared__ float xt[18*18];
    const int t = threadIdx.x;
    const int tx = t & 15, ty = t >> 4;
    const int w0 = blockIdx.x * 16, h0 = blockIdx.y * 16, b = blockIdx.z;
    const float* xb = x + (size_t)b * CH * HWSZ;
    float a0 = 0.f, a1 = 0.f, a2 = 0.f, a3 = 0.f;
    for (int c = 0; c < CH; ++c) {
        for (int i = t; i < 324; i += 256) {
            int iy = i / 18, ix = i - iy * 18;
            int gy = h0 - 1 + iy, gx = w0 - 1 + ix;
            float v = 0.f;
            if (gy >= 0 && gy < HH && gx >= 0 && gx < WW)
                v = xb[(size_t)c * HWSZ + gy * WW + gx];
            xt[i] = v;
        }
        __syncthreads();
        float n[9];
        #pragma unroll
        for (int ky = 0; ky < 3; ++ky)
            #pragma unroll
            for (int kx = 0; kx < 3; ++kx)
                n[ky*3+kx] = xt[(ty+ky)*18 + tx + kx];
        #pragma unroll
        for (int k = 0; k < 9; ++k) {
            a0 = fmaf(n[k], w_rot[(0*CH + c)*9 + k], a0);  // uniform idx -> s_load
            a1 = fmaf(n[k], w_rot[(1*CH + c)*9 + k], a1);
            a2 = fmaf(n[k], w_str[c*9 + k], a2);
            a3 = fmaf(n[k], w_whl[c*9 + k], a3);
        }
        __syncthreads();
    }
    float sv = a0 + b_rot[0], cv = a1 + b_rot[1];
    float inv = 1.0f / sqrtf(sv*sv + cv*cv + 1e-6f);
    sv *= inv; cv *= inv;
    float r  = tanhf(a2 + b_str[0]) * 1.25f + 1.75f;   // A=1.25 B=1.75
    float wr = tanhf(a3 + b_whl[0]) * 1.0f + 2.0f;     // C=1.0  D=2.0
    const int p = (h0 + ty) * WW + (w0 + tx);
    float* ob = offs + (size_t)b * 4 * HWSZ;
    ob[0*HWSZ + p] = sv;
    ob[1*HWSZ + p] = cv;
    ob[2*HWSZ + p] = wr * r;
    ob[3*HWSZ + p] = wr;
}

// ---------------- Kernel B: deformable gather + implicit GEMM ----------------
// Block: 64 consecutive pixels (one b), all 64 output channels. 256 threads.
__global__ __launch_bounds__(256) void deform_kernel(
    const float* __restrict__ x, const float* __restrict__ w_main,
    const float* __restrict__ offs, float* __restrict__ out)
{
    __shared__ float val_lds[KC][64];  // [c_local*9+k][px]
    __shared__ float wm_lds[KC][64];   // [c_local*9+k][o]
    const int t = threadIdx.x;
    const int b = blockIdx.y;
    const int p0 = blockIdx.x * 64;    // 64 | W so strip stays in one row
    const int px = t & 63;
    const int cg = t >> 6;             // 0..3
    const int p = p0 + px;
    const float hh  = (float)(p >> 7);        // H row (W=128)
    const float wwf = (float)(p & (WW - 1));  // col
    const float* ob = offs + (size_t)b * 4 * HWSZ;
    const float sv = ob[0*HWSZ + p];
    const float cv = ob[1*HWSZ + p];
    const float av = ob[2*HWSZ + p];   // wr*r
    const float wv = ob[3*HWSZ + p];   // wr
    const float* xb = x + (size_t)b * CH * HWSZ;

    float acc[4][4];
    #pragma unroll
    for (int i = 0; i < 4; ++i)
        #pragma unroll
        for (int j = 0; j < 4; ++j) acc[i][j] = 0.f;

    const int pg = (t & 15) * 4;   // pixel sub-tile base
    const int og = (t >> 4) * 4;   // output-channel sub-tile base

    for (int c0 = 0; c0 < CH; c0 += CC) {
        // stage w_main chunk transposed: wm_lds[cl*9+k][o] = w_main[o][c0+cl][k]
        {
            const int o = t & 63;
            for (int i = t >> 6; i < CC; i += 4) {
                #pragma unroll
                for (int k = 0; k < 9; ++k)
                    wm_lds[i*9 + k][o] = w_main[(size_t)o*(CH*9) + (c0 + i)*9 + k];
            }
        }
        // gather val chunk: each thread does its px for 4 c's per k
        #pragma unroll 3
        for (int k = 0; k < 9; ++k) {
            const float kyf = (float)(k / 3) - 1.f;
            const float kxf = (float)(k % 3) - 1.f;
            const float o0v = kyf * av;
            const float o1v = kxf * wv;
            const float pyf = hh  + cv * o0v + sv * o1v;
            const float pxf = wwf - sv * o0v + cv * o1v;
            const float y0f = floorf(pyf), x0f = floorf(pxf);
            const float ly = pyf - y0f, lx = pxf - x0f;
            const int y0 = (int)y0f, x0i = (int)x0f;
            const int y1 = y0 + 1, x1 = x0i + 1;
            const bool vy0 = (y0 >= 0) && (y0 < HH);
            const bool vy1 = (y1 >= 0) && (y1 < HH);
            const bool vx0 = (x0i >= 0) && (x0i < WW);
            const bool vx1 = (x1 >= 0) && (x1 < WW);
            const float w00 = (1.f-ly)*(1.f-lx) * ((vy0 && vx0) ? 1.f : 0.f);
            const float w01 = (1.f-ly)*lx       * ((vy0 && vx1) ? 1.f : 0.f);
            const float w10 = ly*(1.f-lx)       * ((vy1 && vx0) ? 1.f : 0.f);
            const float w11 = ly*lx             * ((vy1 && vx1) ? 1.f : 0.f);
            const int iy0 = min(max(y0, 0), HH-1), iy1 = min(max(y1, 0), HH-1);
            const int ix0 = min(max(x0i, 0), WW-1), ix1 = min(max(x1, 0), WW-1);
            const int i00 = iy0*WW + ix0, i01 = iy0*WW + ix1;
            const int i10 = iy1*WW + ix0, i11 = iy1*WW + ix1;
            #pragma unroll
            for (int j = 0; j < 4; ++j) {
                const int cl = cg + j*4;
                const float* xp = xb + (size_t)(c0 + cl) * HWSZ;
                float g = w00*xp[i00] + w01*xp[i01] + w10*xp[i10] + w11*xp[i11];
                val_lds[cl*9 + k][px] = g;
            }
        }
        __syncthreads();
        // 64px x 64o GEMM over this K-chunk; thread = 4px x 4o
        #pragma unroll 4
        for (int ck = 0; ck < KC; ++ck) {
            const float4 a4 = *(const float4*)&val_lds[ck][pg];
            const float4 b4 = *(const float4*)&wm_lds[ck][og];
            const float a[4] = {a4.x, a4.y, a4.z, a4.w};
            const float bb[4] = {b4.x, b4.y, b4.z, b4.w};
            #pragma unroll
            for (int i = 0; i < 4; ++i)
                #pragma unroll
                for (int j = 0; j < 4; ++j)
                    acc[i][j] = fmaf(a[i], bb[j], acc[i][j]);
        }
        __syncthreads();
    }
    // write out: float4 over pixels, coalesced-ish
    #pragma unroll
    for (int j = 0; j < 4; ++j) {
        float4 v = make_float4(acc[0][j], acc[1][j], acc[2][j], acc[3][j]);
        *(float4*)&out[((size_t)b*OC + og + j)*HWSZ + p0 + pg] = v;
    }
}

extern "C" void kernel_launch(void* const* d_in, const int* in_sizes, int n_in,
                              void* d_out, int out_size, void* d_ws, size_t ws_size,
                              hipStream_t stream)
{
    const float* x      = (const float*)d_in[0];
    const float* w_main = (const float*)d_in[1];
    const float* w_rot  = (const float*)d_in[2];
    const float* b_rot  = (const float*)d_in[3];
    const float* w_str  = (const float*)d_in[4];
    const float* b_str  = (const float*)d_in[5];
    const float* w_whl  = (const float*)d_in[6];
    const float* b_whl  = (const float*)d_in[7];
    float* out  = (float*)d_out;
    float* offs = (float*)d_ws;   // 8*4*128*128*4 = 2 MB

    offsets_kernel<<<dim3(WW/16, HH/16, NB), 256, 0, stream>>>(
        x, w_rot, b_rot, w_str, b_str, w_whl, b_whl, offs);
    deform_kernel<<<dim3(HWSZ/64, NB), 256, 0, stream>>>(
        x, w_main, offs, out);
}

// Round 2
// 277.212 us; speedup vs baseline: 1.6792x; 1.6792x over previous
//
#include <hip/hip_runtime.h>
#include <hip/hip_bf16.h>
#include <math.h>

#define HH 128
#define WW 128
#define HWSZ (HH*WW)
#define CH 64
#define OC 64
#define NB 8

// ws layout: xT bf16 [b][h][w][c]  (16777216 B)
//            offs float4 [b][p]    (2097152 B)
//            wmT float [k][c][o]   (147456 B)
#define XT_BYTES   (16777216u)
#define OFFS_BYTES (2097152u)

// ---------------- Kernel T: x NCHW fp32 -> xT NHWC bf16 ----------------
__global__ __launch_bounds__(256) void transpose_kernel(
    const float* __restrict__ x, __hip_bfloat16* __restrict__ xT)
{
    __shared__ float tile[64][65];
    const int t = threadIdx.x;
    const int w0 = (blockIdx.x & 1) * 64;
    const int h  = blockIdx.x >> 1;
    const int b  = blockIdx.y;
    const float* xb = x + (size_t)b * CH * HWSZ + h * WW + w0;
    {
        const int w = t & 63, c0 = (t >> 6) * 16;
        #pragma unroll
        for (int j = 0; j < 16; ++j)
            tile[c0 + j][w] = xb[(size_t)(c0 + j) * HWSZ + w];
    }
    __syncthreads();
    {
        const int c = t & 63, wq = t >> 6;
        __hip_bfloat16* o = xT + ((size_t)b * HWSZ + h * WW + w0) * 64;
        #pragma unroll
        for (int j = 0; j < 16; ++j) {
            const int w = wq * 16 + j;
            o[(size_t)w * 64 + c] = __float2bfloat16(tile[c][w]);
        }
    }
}

// ---------------- Kernel W: w_main [o][c][k] -> wmT [k][c][o] ----------------
__global__ __launch_bounds__(256) void wmt_kernel(
    const float* __restrict__ wm, float* __restrict__ wmT)
{
    const int i = blockIdx.x * 256 + threadIdx.x;   // < 36864
    const int k = i >> 12;
    const int r = i & 4095;
    const int c = r >> 6;
    const int o = r & 63;
    wmT[i] = wm[(size_t)o * (CH * 9) + c * 9 + k];
}

// ---------------- Kernel A: per-pixel offset params (direct, no LDS) ----------------
__global__ __launch_bounds__(256) void offsets_kernel(
    const float* __restrict__ x,
    const float* __restrict__ w_rot, const float* __restrict__ b_rot,
    const float* __restrict__ w_str, const float* __restrict__ b_str,
    const float* __restrict__ w_whl, const float* __restrict__ b_whl,
    float4* __restrict__ offs)
{
    const int t = threadIdx.x;
    const int p = blockIdx.x * 256 + t;
    const int b = blockIdx.y;
    const int h = p >> 7, w = p & (WW - 1);
    int   idx[9];
    float msk[9];
    #pragma unroll
    for (int d = 0; d < 9; ++d) {
        const int dy = d / 3 - 1, dx = d % 3 - 1;
        const int hy = h + dy, wx = w + dx;
        const bool v = (hy >= 0) && (hy < HH) && (wx >= 0) && (wx < WW);
        idx[d] = min(max(hy, 0), HH - 1) * WW + min(max(wx, 0), WW - 1);
        msk[d] = v ? 1.f : 0.f;
    }
    float a0 = 0.f, a1 = 0.f, a2 = 0.f, a3 = 0.f;
    const float* xb = x + (size_t)b * CH * HWSZ;
    for (int c = 0; c < CH; ++c) {
        const float* xc = xb + (size_t)c * HWSZ;
        float n[9];
        #pragma unroll
        for (int d = 0; d < 9; ++d) n[d] = xc[idx[d]] * msk[d];
        #pragma unroll
        for (int d = 0; d < 9; ++d) {
            a0 = fmaf(n[d], w_rot[c * 9 + d], a0);
            a1 = fmaf(n[d], w_rot[CH * 9 + c * 9 + d], a1);
            a2 = fmaf(n[d], w_str[c * 9 + d], a2);
            a3 = fmaf(n[d], w_whl[c * 9 + d], a3);
        }
    }
    float sv = a0 + b_rot[0], cv = a1 + b_rot[1];
    const float inv = 1.0f / sqrtf(sv * sv + cv * cv + 1e-6f);
    const float r  = tanhf(a2 + b_str[0]) * 1.25f + 1.75f;   // A,B
    const float wr = tanhf(a3 + b_whl[0]) * 1.0f + 2.0f;     // C,D
    offs[(size_t)b * HWSZ + p] = make_float4(sv * inv, cv * inv, wr * r, wr);
}

// ---------------- Kernel B: gather + implicit GEMM, tap-chunked ----------------
// Block: 64 px x 64 oc, 256 threads, K-chunk = one tap (64 channels).
union U8 { uint4 q[2]; unsigned int u[8]; };

__device__ inline void bf2x(unsigned int u, float& lo, float& hi) {
    union { unsigned int v; float f; } a, b;
    a.v = u << 16; b.v = u & 0xFFFF0000u;
    lo = a.f; hi = b.f;
}

__global__ __launch_bounds__(256, 4) void deform_kernel(
    const __hip_bfloat16* __restrict__ xT, const float* __restrict__ wmT,
    const float4* __restrict__ offs, float* __restrict__ out)
{
    __shared__ float val_lds[64][64];  // [c][px]
    __shared__ float wm_lds[64][64];   // [c][o]
    const int t = threadIdx.x;
    const int b = blockIdx.y;
    const int p0 = blockIdx.x * 64;
    const int px = t & 63;
    const int cbase = (t >> 6) * 16;   // wave-uniform channel slab
    const int p = p0 + px;
    const float hh  = (float)(p >> 7);
    const float wwf = (float)(p & (WW - 1));
    const float4 o4 = offs[(size_t)b * HWSZ + p];
    const float sv = o4.x, cv = o4.y, av = o4.z, wv = o4.w;
    const __hip_bfloat16* xb = xT + (size_t)b * HWSZ * 64;

    float acc[4][4] = {};
    const int pg = (t & 15) * 4;
    const int og = (t >> 4) * 4;

    for (int k = 0; k < 9; ++k) {
        // stage wm tap k: 16 consecutive floats per thread, coalesced
        {
            const float4* src = (const float4*)(wmT + (size_t)k * 4096) + t * 4;
            float4* dst = ((float4*)&wm_lds[0][0]) + t * 4;
            #pragma unroll
            for (int j = 0; j < 4; ++j) dst[j] = src[j];
        }
        // geometry for this lane's pixel at tap k
        const float kyf = (float)(k / 3) - 1.f;
        const float kxf = (float)(k % 3) - 1.f;
        const float o0v = kyf * av;
        const float o1v = kxf * wv;
        const float pyf = hh  + cv * o0v + sv * o1v;
        const float pxf = wwf - sv * o0v + cv * o1v;
        const float y0f = floorf(pyf), x0f = floorf(pxf);
        const float ly = pyf - y0f, lx = pxf - x0f;
        const int y0 = (int)y0f, x0i = (int)x0f;
        const int y1 = y0 + 1, x1 = x0i + 1;
        const bool vy0 = (y0 >= 0) && (y0 < HH);
        const bool vy1 = (y1 >= 0) && (y1 < HH);
        const bool vx0 = (x0i >= 0) && (x0i < WW);
        const bool vx1 = (x1 >= 0) && (x1 < WW);
        const float w00 = (1.f - ly) * (1.f - lx) * ((vy0 && vx0) ? 1.f : 0.f);
        const float w01 = (1.f - ly) * lx         * ((vy0 && vx1) ? 1.f : 0.f);
        const float w10 = ly * (1.f - lx)         * ((vy1 && vx0) ? 1.f : 0.f);
        const float w11 = ly * lx                 * ((vy1 && vx1) ? 1.f : 0.f);
        const int iy0 = min(max(y0, 0), HH - 1), iy1 = min(max(y1, 0), HH - 1);
        const int ix0 = min(max(x0i, 0), WW - 1), ix1 = min(max(x1, 0), WW - 1);
        const int i00 = iy0 * WW + ix0, i01 = iy0 * WW + ix1;
        const int i10 = iy1 * WW + ix0, i11 = iy1 * WW + ix1;

        // 4 corners x 16 channels (bf16), 2x dwordx4 each
        U8 g00, g01, g10, g11;
        {
            const uint4* c00 = (const uint4*)(xb + (size_t)i00 * 64 + cbase);
            const uint4* c01 = (const uint4*)(xb + (size_t)i01 * 64 + cbase);
            const uint4* c10 = (const uint4*)(xb + (size_t)i10 * 64 + cbase);
            const uint4* c11 = (const uint4*)(xb + (size_t)i11 * 64 + cbase);
            g00.q[0] = c00[0]; g00.q[1] = c00[1];
            g01.q[0] = c01[0]; g01.q[1] = c01[1];
            g10.q[0] = c10[0]; g10.q[1] = c10[1];
            g11.q[0] = c11[0]; g11.q[1] = c11[1];
        }
        #pragma unroll
        for (int j = 0; j < 8; ++j) {
            float a_lo, a_hi, b_lo, b_hi, c_lo, c_hi, d_lo, d_hi;
            bf2x(g00.u[j], a_lo, a_hi);
            bf2x(g01.u[j], b_lo, b_hi);
            bf2x(g10.u[j], c_lo, c_hi);
            bf2x(g11.u[j], d_lo, d_hi);
            const float v_lo = w00 * a_lo + w01 * b_lo + w10 * c_lo + w11 * d_lo;
            const float v_hi = w00 * a_hi + w01 * b_hi + w10 * c_hi + w11 * d_hi;
            val_lds[cbase + 2 * j][px]     = v_lo;
            val_lds[cbase + 2 * j + 1][px] = v_hi;
        }
        __syncthreads();
        // 64px x 64oc GEMM over 64 channels of this tap
        #pragma unroll 8
        for (int ck = 0; ck < 64; ++ck) {
            const float4 a4 = *(const float4*)&val_lds[ck][pg];
            const float4 b4 = *(const float4*)&wm_lds[ck][og];
            const float a[4]  = {a4.x, a4.y, a4.z, a4.w};
            const float bb[4] = {b4.x, b4.y, b4.z, b4.w};
            #pragma unroll
            for (int i = 0; i < 4; ++i)
                #pragma unroll
                for (int j = 0; j < 4; ++j)
                    acc[i][j] = fmaf(a[i], bb[j], acc[i][j]);
        }
        __syncthreads();
    }
    #pragma unroll
    for (int j = 0; j < 4; ++j) {
        float4 v = make_float4(acc[0][j], acc[1][j], acc[2][j], acc[3][j]);
        *(float4*)&out[((size_t)b * OC + og + j) * HWSZ + p0 + pg] = v;
    }
}

extern "C" void kernel_launch(void* const* d_in, const int* in_sizes, int n_in,
                              void* d_out, int out_size, void* d_ws, size_t ws_size,
                              hipStream_t stream)
{
    const float* x      = (const float*)d_in[0];
    const float* w_main = (const float*)d_in[1];
    const float* w_rot  = (const float*)d_in[2];
    const float* b_rot  = (const float*)d_in[3];
    const float* w_str  = (const float*)d_in[4];
    const float* b_str  = (const float*)d_in[5];
    const float* w_whl  = (const float*)d_in[6];
    const float* b_whl  = (const float*)d_in[7];
    float* out = (float*)d_out;

    char* ws = (char*)d_ws;
    __hip_bfloat16* xT = (__hip_bfloat16*)ws;
    float4* offs = (float4*)(ws + XT_BYTES);
    float*  wmT  = (float*)(ws + XT_BYTES + OFFS_BYTES);

    transpose_kernel<<<dim3(HH * 2, NB), 256, 0, stream>>>(x, xT);
    wmt_kernel<<<dim3(144), 256, 0, stream>>>(w_main, wmT);
    offsets_kernel<<<dim3(HWSZ / 256, NB), 256, 0, stream>>>(
        x, w_rot, b_rot, w_str, b_str, w_whl, b_whl, offs);
    deform_kernel<<<dim3(HWSZ / 64, NB), 256, 0, stream>>>(xT, wmT, offs, out);
}

// Round 3
// 265.306 us; speedup vs baseline: 1.7546x; 1.0449x over previous
//
#include <hip/hip_runtime.h>
#include <hip/hip_bf16.h>
#include <math.h>

#define HH 128
#define WW 128
#define HWSZ (HH*WW)
#define CH 64
#define OC 64
#define NB 8

// ws layout: xT bf16 [b][h][w][c]      (16777216 B)
//            offs float4 [b][p]        (2097152 B)
//            wmT2 bf16 [k][oc][ch]     (73728 B)
#define XT_BYTES   (16777216u)
#define OFFS_BYTES (2097152u)

typedef __attribute__((ext_vector_type(8))) short bf16x8_t;   // 8 bf16 (4 VGPRs)
typedef __attribute__((ext_vector_type(4))) float f32x4_t;    // 4 fp32 acc

// ---------------- Kernel T: x NCHW fp32 -> xT NHWC bf16 ----------------
__global__ __launch_bounds__(256) void transpose_kernel(
    const float* __restrict__ x, __hip_bfloat16* __restrict__ xT)
{
    __shared__ float tile[64][65];
    const int t = threadIdx.x;
    const int w0 = (blockIdx.x & 1) * 64;
    const int h  = blockIdx.x >> 1;
    const int b  = blockIdx.y;
    const float* xb = x + (size_t)b * CH * HWSZ + h * WW + w0;
    {
        const int w = t & 63, c0 = (t >> 6) * 16;
        #pragma unroll
        for (int j = 0; j < 16; ++j)
            tile[c0 + j][w] = xb[(size_t)(c0 + j) * HWSZ + w];
    }
    __syncthreads();
    {
        const int c = t & 63, wq = t >> 6;
        __hip_bfloat16* o = xT + ((size_t)b * HWSZ + h * WW + w0) * 64;
        #pragma unroll
        for (int j = 0; j < 16; ++j) {
            const int w = wq * 16 + j;
            o[(size_t)w * 64 + c] = __float2bfloat16(tile[c][w]);
        }
    }
}

// ---------------- Kernel W: w_main [o][c][k] fp32 -> wmT2 [k][o][c] bf16 ----------------
__global__ __launch_bounds__(256) void wmt_kernel(
    const float* __restrict__ wm, __hip_bfloat16* __restrict__ wmT2)
{
    const int i = blockIdx.x * 256 + threadIdx.x;   // < 9*64*64 = 36864
    const int k = i >> 12;          // /4096
    const int r = i & 4095;
    const int o = r >> 6;
    const int c = r & 63;
    wmT2[i] = __float2bfloat16(wm[(size_t)o * (CH * 9) + c * 9 + k]);
}

// ---------------- Kernel A: offsets, row-slab LDS staging (fp32 exact) ----------------
__global__ __launch_bounds__(256) void offsets_kernel(
    const float* __restrict__ x,
    const float* __restrict__ w_rot, const float* __restrict__ b_rot,
    const float* __restrict__ w_str, const float* __restrict__ b_str,
    const float* __restrict__ w_whl, const float* __restrict__ b_whl,
    float4* __restrict__ offs)
{
    __shared__ float xs[16][4][WW];   // 32 KB: 16 ch x 4 rows x 128 w
    const int t = threadIdx.x;
    const int b = blockIdx.y;
    const int h0 = blockIdx.x * 2;          // block handles rows h0, h0+1
    const int r = t >> 7;                   // 0..1
    const int w = t & 127;
    const int wl = max(w - 1, 0), wr2 = min(w + 1, WW - 1);
    const float ml = (w > 0) ? 1.f : 0.f, mr = (w < WW - 1) ? 1.f : 0.f;
    float a0 = 0.f, a1 = 0.f, a2 = 0.f, a3 = 0.f;
    const float* xb = x + (size_t)b * CH * HWSZ;

    for (int c0 = 0; c0 < CH; c0 += 16) {
        __syncthreads();
        // load 16 ch x 4 rows (h0-1 .. h0+2) x 128 w, float4 coalesced
        for (int i = t; i < 2048; i += 256) {
            const int ch  = i >> 7;          // /128 float4s per ch
            const int rem = i & 127;
            const int rr  = rem >> 5;        // row 0..3
            const int w4  = (rem & 31) * 4;
            const int grow = h0 - 1 + rr;
            float4 v = make_float4(0.f, 0.f, 0.f, 0.f);
            if (grow >= 0 && grow < HH)
                v = *(const float4*)&xb[((size_t)(c0 + ch) * HH + grow) * WW + w4];
            *(float4*)&xs[ch][rr][w4] = v;
        }
        __syncthreads();
        #pragma unroll 4
        for (int ch = 0; ch < 16; ++ch) {
            const int c = c0 + ch;
            #pragma unroll
            for (int dy = 0; dy < 3; ++dy) {
                const float* row = &xs[ch][r + dy][0];
                const float nl = row[wl] * ml;
                const float nc = row[w];
                const float nr = row[wr2] * mr;
                const int d0 = c * 9 + dy * 3;
                a0 = fmaf(nl, w_rot[d0 + 0], a0); a0 = fmaf(nc, w_rot[d0 + 1], a0); a0 = fmaf(nr, w_rot[d0 + 2], a0);
                a1 = fmaf(nl, w_rot[576 + d0 + 0], a1); a1 = fmaf(nc, w_rot[576 + d0 + 1], a1); a1 = fmaf(nr, w_rot[576 + d0 + 2], a1);
                a2 = fmaf(nl, w_str[d0 + 0], a2); a2 = fmaf(nc, w_str[d0 + 1], a2); a2 = fmaf(nr, w_str[d0 + 2], a2);
                a3 = fmaf(nl, w_whl[d0 + 0], a3); a3 = fmaf(nc, w_whl[d0 + 1], a3); a3 = fmaf(nr, w_whl[d0 + 2], a3);
            }
        }
    }
    float sv = a0 + b_rot[0], cvv = a1 + b_rot[1];
    const float inv = 1.0f / sqrtf(sv * sv + cvv * cvv + 1e-6f);
    const float rr = tanhf(a2 + b_str[0]) * 1.25f + 1.75f;   // A,B
    const float wq = tanhf(a3 + b_whl[0]) * 1.0f + 2.0f;     // C,D
    offs[(size_t)b * HWSZ + (h0 + r) * WW + w] = make_float4(sv * inv, cvv * inv, wq * rr, wq);
}

// ---------------- Kernel B: gather + MFMA implicit GEMM, no main-loop LDS ----------------
__device__ inline void bf2x(unsigned int u, float& lo, float& hi) {
    union { unsigned int v; float f; } a, b;
    a.v = u << 16; b.v = u & 0xFFFF0000u;
    lo = a.f; hi = b.f;
}

__global__ __launch_bounds__(256, 4) void deform_kernel(
    const __hip_bfloat16* __restrict__ xT, const __hip_bfloat16* __restrict__ wmT2,
    const float4* __restrict__ offs, float* __restrict__ out)
{
    __shared__ float ots[64][67];   // [px][oc], epilogue only
    const int t  = threadIdx.x;
    const int wv = t >> 6;          // wave id: px strip [wv*16, wv*16+16)
    const int l  = t & 63;
    const int lm = l & 15;          // A-row (px) / B-col (oc)
    const int lg = l >> 4;          // k-group: 8-channel slab
    const int b  = blockIdx.y;
    const int p0 = blockIdx.x * 64;
    const int p  = p0 + wv * 16 + lm;
    const float hh  = (float)(p >> 7);
    const float wwf = (float)(p & (WW - 1));
    const float4 o4 = offs[(size_t)b * HWSZ + p];
    const float sv = o4.x, cv = o4.y, av = o4.z, wvl = o4.w;
    const __hip_bfloat16* xb = xT + (size_t)b * HWSZ * 64;

    f32x4_t acc0 = {0.f, 0.f, 0.f, 0.f};
    f32x4_t acc1 = acc0, acc2 = acc0, acc3 = acc0;

    #pragma unroll 1
    for (int k = 0; k < 9; ++k) {
        const float kyf = (float)(k / 3) - 1.f;
        const float kxf = (float)(k % 3) - 1.f;
        const float o0v = kyf * av;
        const float o1v = kxf * wvl;
        const float pyf = hh  + cv * o0v + sv * o1v;
        const float pxf = wwf - sv * o0v + cv * o1v;
        const float y0f = floorf(pyf), x0f = floorf(pxf);
        const float ly = pyf - y0f, lx = pxf - x0f;
        const int y0 = (int)y0f, x0i = (int)x0f;
        const int y1 = y0 + 1, x1 = x0i + 1;
        const bool vy0 = (y0 >= 0) && (y0 < HH);
        const bool vy1 = (y1 >= 0) && (y1 < HH);
        const bool vx0 = (x0i >= 0) && (x0i < WW);
        const bool vx1 = (x1 >= 0) && (x1 < WW);
        const float w00 = (1.f - ly) * (1.f - lx) * ((vy0 && vx0) ? 1.f : 0.f);
        const float w01 = (1.f - ly) * lx         * ((vy0 && vx1) ? 1.f : 0.f);
        const float w10 = ly * (1.f - lx)         * ((vy1 && vx0) ? 1.f : 0.f);
        const float w11 = ly * lx                 * ((vy1 && vx1) ? 1.f : 0.f);
        const int iy0 = min(max(y0, 0), HH - 1), iy1 = min(max(y1, 0), HH - 1);
        const int ix0 = min(max(x0i, 0), WW - 1), ix1 = min(max(x1, 0), WW - 1);
        const __hip_bfloat16* b00 = xb + (size_t)(iy0 * WW + ix0) * 64;
        const __hip_bfloat16* b01 = xb + (size_t)(iy0 * WW + ix1) * 64;
        const __hip_bfloat16* b10 = xb + (size_t)(iy1 * WW + ix0) * 64;
        const __hip_bfloat16* b11 = xb + (size_t)(iy1 * WW + ix1) * 64;

        #pragma unroll
        for (int s = 0; s < 2; ++s) {
            const int cb = s * 32 + lg * 8;   // this lane's 8-channel slab
            const uint4 q00 = *(const uint4*)(b00 + cb);
            const uint4 q01 = *(const uint4*)(b01 + cb);
            const uint4 q10 = *(const uint4*)(b10 + cb);
            const uint4 q11 = *(const uint4*)(b11 + cb);
            const unsigned int* u00 = (const unsigned int*)&q00;
            const unsigned int* u01 = (const unsigned int*)&q01;
            const unsigned int* u10 = (const unsigned int*)&q10;
            const unsigned int* u11 = (const unsigned int*)&q11;
            union { unsigned int u[4]; bf16x8_t v; } af;
            #pragma unroll
            for (int j = 0; j < 4; ++j) {
                float alo, ahi, blo, bhi, clo, chi, dlo, dhi;
                bf2x(u00[j], alo, ahi);
                bf2x(u01[j], blo, bhi);
                bf2x(u10[j], clo, chi);
                bf2x(u11[j], dlo, dhi);
                const float v_lo = w00 * alo + w01 * blo + w10 * clo + w11 * dlo;
                const float v_hi = w00 * ahi + w01 * bhi + w10 * chi + w11 * dhi;
                union { __hip_bfloat162 h; unsigned int u; } pk;
                pk.h = __float22bfloat162_rn(make_float2(v_lo, v_hi));
                af.u[j] = pk.u;
            }
            // B-fragments: wmT2[k][oc = n*16+lm][cb..cb+7], L1-hot
            const __hip_bfloat16* wp = wmT2 + ((size_t)k * 64 + lm) * 64 + cb;
            const bf16x8_t bf0 = *(const bf16x8_t*)(wp);
            const bf16x8_t bf1 = *(const bf16x8_t*)(wp + 1024);
            const bf16x8_t bf2v = *(const bf16x8_t*)(wp + 2048);
            const bf16x8_t bf3 = *(const bf16x8_t*)(wp + 3072);
            acc0 = __builtin_amdgcn_mfma_f32_16x16x32_bf16(af.v, bf0, acc0, 0, 0, 0);
            acc1 = __builtin_amdgcn_mfma_f32_16x16x32_bf16(af.v, bf1, acc1, 0, 0, 0);
            acc2 = __builtin_amdgcn_mfma_f32_16x16x32_bf16(af.v, bf2v, acc2, 0, 0, 0);
            acc3 = __builtin_amdgcn_mfma_f32_16x16x32_bf16(af.v, bf3, acc3, 0, 0, 0);
        }
    }
    // epilogue: C/D layout col=lane&15 (oc), row=(lane>>4)*4+reg (px)
    const int pxw = wv * 16 + lg * 4;
    #pragma unroll
    for (int rg = 0; rg < 4; ++rg) {
        ots[pxw + rg][ 0 + lm] = acc0[rg];
        ots[pxw + rg][16 + lm] = acc1[rg];
        ots[pxw + rg][32 + lm] = acc2[rg];
        ots[pxw + rg][48 + lm] = acc3[rg];
    }
    __syncthreads();
    const int oo = t >> 2;
    const int q  = (t & 3) * 16;
    float4* dst = (float4*)&out[((size_t)b * OC + oo) * HWSZ + p0 + q];
    #pragma unroll
    for (int j2 = 0; j2 < 4; ++j2) {
        dst[j2] = make_float4(ots[q + j2 * 4 + 0][oo], ots[q + j2 * 4 + 1][oo],
                              ots[q + j2 * 4 + 2][oo], ots[q + j2 * 4 + 3][oo]);
    }
}

extern "C" void kernel_launch(void* const* d_in, const int* in_sizes, int n_in,
                              void* d_out, int out_size, void* d_ws, size_t ws_size,
                              hipStream_t stream)
{
    const float* x      = (const float*)d_in[0];
    const float* w_main = (const float*)d_in[1];
    const float* w_rot  = (const float*)d_in[2];
    const float* b_rot  = (const float*)d_in[3];
    const float* w_str  = (const float*)d_in[4];
    const float* b_str  = (const float*)d_in[5];
    const float* w_whl  = (const float*)d_in[6];
    const float* b_whl  = (const float*)d_in[7];
    float* out = (float*)d_out;

    char* ws = (char*)d_ws;
    __hip_bfloat16* xT   = (__hip_bfloat16*)ws;
    float4*         offs = (float4*)(ws + XT_BYTES);
    __hip_bfloat16* wmT2 = (__hip_bfloat16*)(ws + XT_BYTES + OFFS_BYTES);

    transpose_kernel<<<dim3(HH * 2, NB), 256, 0, stream>>>(x, xT);
    wmt_kernel<<<dim3(144), 256, 0, stream>>>(w_main, wmT2);
    offsets_kernel<<<dim3(HH / 2, NB), 256, 0, stream>>>(
        x, w_rot, b_rot, w_str, b_str, w_whl, b_whl, offs);
    deform_kernel<<<dim3(HWSZ / 64, NB), 256, 0, stream>>>(xT, wmT2, offs, out);
}